// Round 9
// baseline (81.860 us; speedup 1.0000x reference)
//
#include <hip/hip_runtime.h>
#include <math.h>

// Problem constants (from setup_inputs: batch=1024, dim_z=32, n_samples=32, agg_size=256)
#define B    1024
#define D    32
#define NS   32
#define AGG  256
#define NC   (B / AGG)      // 4 chunks
#define M    (AGG * NS)     // 8192 samples per chunk
#define NJB  4              // j-blocks per (c,k)
#define JB   (M / NJB)      // 2048 samples per block
#define TJ   (JB / 256)     // 8 samples per thread
#define NBLK (NC * D * NJB) // 512 blocks -> 2 blocks/CU -> 8 waves/CU

typedef float v2f __attribute__((ext_vector_type(2)));

// ws layout: [0]: uint counter | @256: float partial[NBLK] (2KB) | @8192: float4 params
// params[(c*D+k)*AGG + i] = {A, B, C, sd}:
//   arg(z) = A*z^2 + B*z + C = -0.5*log2e*((z-mu)^2*exp(-lv) + lv),  sd = exp(0.5*lv)
//   (mu recoverable as -0.5*B/A)
__global__ __launch_bounds__(256) void ksetup(const float* __restrict__ mean,
                                              const float* __restrict__ logvar,
                                              float4* __restrict__ params,
                                              unsigned* __restrict__ counter)
{
    constexpr float LOG2E = 1.4426950408889634f;
    const int tid = blockIdx.x * 256 + threadIdx.x;   // over B*D = 32768, k fastest
    if (tid == 0) counter[0] = 0u;                    // reset last-block counter
    const int row = tid >> 5;        // 0..1023  (global component row)
    const int k   = tid & (D - 1);
    const int c   = row >> 8;
    const int i   = row & (AGG - 1);
    const float mu = mean[tid];      // coalesced
    const float lv = logvar[tid];
    const float ev = __builtin_amdgcn_exp2f(-lv * LOG2E);      // exp(-lv); lv~N(0,1): safe
    params[((c * D + k) << 8) | i] =
        make_float4(-0.5f * LOG2E * ev,
                    LOG2E * mu * ev,
                    -0.5f * LOG2E * fmaf(mu * mu, ev, lv),
                    __builtin_amdgcn_exp2f(0.5f * LOG2E * lv)); // sd = exp(0.5*lv)
}

__global__ __launch_bounds__(256) void kmain(const float* __restrict__ eps,
                                             const float4* __restrict__ params,
                                             float* __restrict__ partial,
                                             unsigned* __restrict__ counter,
                                             float* __restrict__ out)
{
    constexpr float LN2 = 0.6931471805599453f;
    const int bid = blockIdx.x;
    const int c   = bid / (D * NJB);
    const int rem = bid - c * (D * NJB);
    const int k   = rem / NJB;
    const int jb  = rem - k * NJB;
    const int j0  = jb * JB;
    const int t   = threadIdx.x;

    // Block-uniform param table base -> batched s_load (scalar path; K$-resident).
    const float4* __restrict__ pk = params + ((c * D + k) << 8);

    // Scattered eps gathers (L2 latency hides under the z-prologue).
    float ev[TJ];
#pragma unroll
    for (int u = 0; u < TJ; ++u)
        ev[u] = eps[(size_t)(c * M + j0 + t + 256 * u) * D + k];

    // z for this thread's TJ samples (z2 flat layout == eps flat layout).
    float zv[TJ];
#pragma unroll
    for (int u = 0; u < TJ; ++u) {
        const float4 p = pk[(t + 256 * u) >> 5];         // own component
        const float mu = -0.5f * p.y * __builtin_amdgcn_rcpf(p.x);
        zv[u] = fmaf(ev[u], p.w, mu);
    }
    v2f zp[TJ / 2], accv[TJ / 2];
#pragma unroll
    for (int q = 0; q < TJ / 2; ++q) {
        zp[q]   = (v2f){zv[2 * q], zv[2 * q + 1]};
        accv[q] = (v2f){0.f, 0.f};
    }

    // Pairwise loop over 256 components. exp2 computed ON THE FULL-RATE VALU
    // (trans unit measured ~27 cyc/wave-exp across r5-r8 = the old roofline):
    //   x = A z^2 + B z + C;  n = rint(x);  f = x-n in [-0.5,0.5];
    //   2^f by deg-4 Taylor (|rel err|<7e-5);  scale by v_ldexp_f32 (flushes n<<0 to 0).
    // Per pair ~14 full-rate instr (~28 cyc) vs ~54 cyc trans-unit backlog before.
#pragma unroll 4
    for (int i = 0; i < AGG; ++i) {
        const float4 p = pk[i];
        const v2f A2 = (v2f){p.x, p.x};
        const v2f B2 = (v2f){p.y, p.y};
        const v2f C2 = (v2f){p.z, p.z};
#pragma unroll
        for (int q = 0; q < TJ / 2; ++q) {
            const v2f x  = (A2 * zp[q] + B2) * zp[q] + C2;
            const float n0 = rintf(x.x);
            const float n1 = rintf(x.y);
            v2f f = x - (v2f){n0, n1};
            v2f pl = (v2f){0.009618129f, 0.009618129f};
            pl = pl * f + (v2f){0.055504109f, 0.055504109f};
            pl = pl * f + (v2f){0.240226507f, 0.240226507f};
            pl = pl * f + (v2f){0.693147181f, 0.693147181f};
            pl = pl * f + (v2f){1.0f, 1.0f};
            accv[q] += (v2f){ldexpf(pl.x, (int)n0), ldexpf(pl.y, (int)n1)};
        }
    }

    // per-thread contribution: ln(sum_i) + 0.5*z^2 (global constants folded at the end)
    float r = 0.f;
#pragma unroll
    for (int q = 0; q < TJ / 2; ++q) {
        r += LN2 * __builtin_amdgcn_logf(accv[q].x) + 0.5f * zp[q].x * zp[q].x;
        r += LN2 * __builtin_amdgcn_logf(accv[q].y) + 0.5f * zp[q].y * zp[q].y;
    }

    // deterministic block reduction
    for (int off = 32; off > 0; off >>= 1) r += __shfl_down(r, off, 64);
    __shared__ float wsum[4];
    if ((t & 63) == 0) wsum[t >> 6] = r;
    __syncthreads();

    // last-block final reduction (deterministic: fixed-order sum over partial[])
    __shared__ int isLast;
    if (t == 0) {
        partial[bid] = (wsum[0] + wsum[1]) + (wsum[2] + wsum[3]);
        __threadfence();                          // publish partial device-wide
        const unsigned old = atomicAdd(counter, 1u);
        isLast = (old == (unsigned)(NBLK - 1));
    }
    __syncthreads();
    if (isLast) {
        __threadfence();                          // acquire all partials
        double s = 0.0;
#pragma unroll
        for (int i = 0; i < NBLK / 256; ++i) s += (double)partial[i * 256 + t];
        __shared__ double sd[256];
        sd[t] = s;
        __syncthreads();
        for (int off = 128; off > 0; off >>= 1) {
            if (t < off) sd[t] += sd[t + off];
            __syncthreads();
        }
        if (t == 0) {
            // out = total/(nc*M) - D*ln(256)
            out[0] = (float)(sd[0] * (1.0 / (double)(NC * M))
                             - (double)D * 5.545177444479562);
        }
    }
}

extern "C" void kernel_launch(void* const* d_in, const int* in_sizes, int n_in,
                              void* d_out, int out_size, void* d_ws, size_t ws_size,
                              hipStream_t stream)
{
    const float* mean   = (const float*)d_in[0];
    const float* logvar = (const float*)d_in[1];
    const float* eps    = (const float*)d_in[2];
    float* out = (float*)d_out;

    unsigned* counter = (unsigned*)d_ws;
    float*    partial = (float*)((char*)d_ws + 256);    // NBLK floats
    float4*   params  = (float4*)((char*)d_ws + 8192);  // 512KB param table

    ksetup<<<(B * D) / 256, 256, 0, stream>>>(mean, logvar, params, counter);
    kmain<<<NBLK, 256, 0, stream>>>(eps, params, partial, counter, out);
}

// Round 10
// 80.437 us; speedup vs baseline: 1.0177x; 1.0177x over previous
//
#include <hip/hip_runtime.h>
#include <math.h>

// Problem constants (from setup_inputs: batch=1024, dim_z=32, n_samples=32, agg_size=256)
#define B    1024
#define D    32
#define NS   32
#define AGG  256
#define NC   (B / AGG)      // 4 chunks
#define M    (AGG * NS)     // 8192 samples per chunk
#define NJB  4              // j-blocks per (c,k)
#define JB   (M / NJB)      // 2048 samples per block
#define TJ   (JB / 256)     // 8 samples per thread
#define NBLK (NC * D * NJB) // 512 blocks -> 2 blocks/CU -> 8 waves/CU

// ws layout: [0]: uint counter | @256: float partial[NBLK] (2KB) | @8192: float4 params
// params[(c*D+k)*AGG + i] = {A, B, C, sd}:
//   arg(z) = A*z^2 + B*z + C = -0.5*log2e*((z-mu)^2*exp(-lv) + lv),  sd = exp(0.5*lv)
//   (mu recoverable as -0.5*B/A)
__global__ __launch_bounds__(256) void ksetup(const float* __restrict__ mean,
                                              const float* __restrict__ logvar,
                                              float4* __restrict__ params,
                                              unsigned* __restrict__ counter)
{
    constexpr float LOG2E = 1.4426950408889634f;
    const int tid = blockIdx.x * 256 + threadIdx.x;   // over B*D = 32768, k fastest
    if (tid == 0) counter[0] = 0u;                    // reset last-block counter
    const int row = tid >> 5;        // 0..1023  (global component row)
    const int k   = tid & (D - 1);
    const int c   = row >> 8;
    const int i   = row & (AGG - 1);
    const float mu = mean[tid];      // coalesced
    const float lv = logvar[tid];
    const float ev = __builtin_amdgcn_exp2f(-lv * LOG2E);      // exp(-lv); lv~N(0,1): safe
    params[((c * D + k) << 8) | i] =
        make_float4(-0.5f * LOG2E * ev,
                    LOG2E * mu * ev,
                    -0.5f * LOG2E * fmaf(mu * mu, ev, lv),
                    __builtin_amdgcn_exp2f(0.5f * LOG2E * lv)); // sd = exp(0.5*lv)
}

__global__ __launch_bounds__(256) void kmain(const float* __restrict__ eps,
                                             const float4* __restrict__ params,
                                             float* __restrict__ partial,
                                             unsigned* __restrict__ counter,
                                             float* __restrict__ out)
{
    constexpr float LN2 = 0.6931471805599453f;
    const int bid = blockIdx.x;
    const int c   = bid / (D * NJB);
    const int rem = bid - c * (D * NJB);
    const int k   = rem / NJB;
    const int jb  = rem - k * NJB;
    const int j0  = jb * JB;
    const int t   = threadIdx.x;

    // Block-uniform param table base -> batched s_load (scalar path; K$-resident).
    const float4* __restrict__ pk = params + ((c * D + k) << 8);

    // Scattered eps gathers (L2 latency hides under the z-prologue).
    float ev[TJ];
#pragma unroll
    for (int u = 0; u < TJ; ++u)
        ev[u] = eps[(size_t)(c * M + j0 + t + 256 * u) * D + k];

    // z for this thread's TJ samples (z2 flat layout == eps flat layout).
    float zv[TJ], acc[TJ];
#pragma unroll
    for (int u = 0; u < TJ; ++u) {
        const float4 p = pk[(t + 256 * u) >> 5];         // own component
        const float mu = -0.5f * p.y * __builtin_amdgcn_rcpf(p.x);
        zv[u]  = fmaf(ev[u], p.w, mu);
        acc[u] = 0.f;
    }

    // Pairwise loop over 256 components, HYBRID exp:
    //   samples 0-3 -> trans unit (v_exp_f32, measured ~27 cyc/wave-exp ceiling)
    //   samples 4-7 -> full-rate VALU poly: n=rint(x); f=x-n; 2^f deg-3 Taylor
    //                  (rel err <= 6e-4); scale via v_ldexp_f32 (safe underflow).
    // Both pipes run concurrently; poly instrs also fill trans-latency gaps.
#pragma unroll 4
    for (int i = 0; i < AGG; ++i) {
        const float4 p = pk[i];
        float arg[TJ];
#pragma unroll
        for (int u = 0; u < TJ; ++u)
            arg[u] = fmaf(fmaf(p.x, zv[u], p.y), zv[u], p.z);
#pragma unroll
        for (int u = 0; u < TJ / 2; ++u)
            acc[u] += __builtin_amdgcn_exp2f(arg[u]);
#pragma unroll
        for (int u = TJ / 2; u < TJ; ++u) {
            const float n = rintf(arg[u]);
            const float f = arg[u] - n;
            float pl = fmaf(0.0555041f, f, 0.2402265f);   // 2^f Taylor deg-3
            pl = fmaf(pl, f, 0.6931472f);
            pl = fmaf(pl, f, 1.0f);
            acc[u] += ldexpf(pl, (int)n);
        }
    }

    // per-thread contribution: ln(sum_i) + 0.5*z^2 (global constants folded at the end)
    float r = 0.f;
#pragma unroll
    for (int u = 0; u < TJ; ++u)
        r += LN2 * __builtin_amdgcn_logf(acc[u]) + 0.5f * zv[u] * zv[u];

    // deterministic block reduction
    for (int off = 32; off > 0; off >>= 1) r += __shfl_down(r, off, 64);
    __shared__ float wsum[4];
    if ((t & 63) == 0) wsum[t >> 6] = r;
    __syncthreads();

    // last-block final reduction (deterministic: fixed-order sum over partial[])
    __shared__ int isLast;
    if (t == 0) {
        partial[bid] = (wsum[0] + wsum[1]) + (wsum[2] + wsum[3]);
        __threadfence();                          // publish partial device-wide
        const unsigned old = atomicAdd(counter, 1u);
        isLast = (old == (unsigned)(NBLK - 1));
    }
    __syncthreads();
    if (isLast) {
        __threadfence();                          // acquire all partials
        double s = 0.0;
#pragma unroll
        for (int i = 0; i < NBLK / 256; ++i) s += (double)partial[i * 256 + t];
        __shared__ double sd[256];
        sd[t] = s;
        __syncthreads();
        for (int off = 128; off > 0; off >>= 1) {
            if (t < off) sd[t] += sd[t + off];
            __syncthreads();
        }
        if (t == 0) {
            // out = total/(nc*M) - D*ln(256)
            out[0] = (float)(sd[0] * (1.0 / (double)(NC * M))
                             - (double)D * 5.545177444479562);
        }
    }
}

extern "C" void kernel_launch(void* const* d_in, const int* in_sizes, int n_in,
                              void* d_out, int out_size, void* d_ws, size_t ws_size,
                              hipStream_t stream)
{
    const float* mean   = (const float*)d_in[0];
    const float* logvar = (const float*)d_in[1];
    const float* eps    = (const float*)d_in[2];
    float* out = (float*)d_out;

    unsigned* counter = (unsigned*)d_ws;
    float*    partial = (float*)((char*)d_ws + 256);    // NBLK floats
    float4*   params  = (float4*)((char*)d_ws + 8192);  // 512KB param table

    ksetup<<<(B * D) / 256, 256, 0, stream>>>(mean, logvar, params, counter);
    kmain<<<NBLK, 256, 0, stream>>>(eps, params, partial, counter, out);
}

// Round 11
// 43.228 us; speedup vs baseline: 1.8937x; 1.8608x over previous
//
#include <hip/hip_runtime.h>
#include <math.h>

// Problem constants (from setup_inputs: batch=1024, dim_z=32, n_samples=32, agg_size=256)
#define B    1024
#define D    32
#define NS   32
#define AGG  256
#define NC   (B / AGG)      // 4 chunks
#define M    (AGG * NS)     // 8192 samples per chunk
#define NJB  4              // j-blocks per (c,k)
#define JB   (M / NJB)      // 2048 samples per block
#define TJ   (JB / 256)     // 8 samples per thread
#define NBLK (NC * D * NJB) // 512 eval blocks

// Table geometry: L(z)=log2(sum_i 2^arg_i) on z in [-32,32], h=1/16, 1024 nodes/(c,k).
#define TN     1024
#define ZMIN   (-32.0f)
#define INVH   16.0f
#define HH     0.0625f
#define ZCLAMP 31.9f
#define ZOOB   31.0f

// ws layout: [0] uint counter | @256 float partial[512] | @8192 float4 params (512KB)
//            | @532480 float2 table[128*1024] (1MB)   -> NEED = 1581056 bytes
#define WS_PARTIAL 256
#define WS_PARAMS  8192
#define WS_TABLE   532480
#define WS_NEED    1581056

// params[(c*D+k)*AGG + i] = {A, B, C, sd}:  arg(z) = A z^2 + B z + C
//   = -0.5*log2e*((z-mu)^2*exp(-lv) + lv),  sd = exp(0.5*lv), mu = -0.5*B/A
__global__ __launch_bounds__(256) void ksetup(const float* __restrict__ mean,
                                              const float* __restrict__ logvar,
                                              float4* __restrict__ params,
                                              unsigned* __restrict__ counter)
{
    constexpr float LOG2E = 1.4426950408889634f;
    const int tid = blockIdx.x * 256 + threadIdx.x;   // over B*D = 32768, k fastest
    if (tid == 0) counter[0] = 0u;                    // reset last-block counter
    const int row = tid >> 5;
    const int k   = tid & (D - 1);
    const int c   = row >> 8;
    const int i   = row & (AGG - 1);
    const float mu = mean[tid];
    const float lv = logvar[tid];
    const float ev = __builtin_amdgcn_exp2f(-lv * LOG2E);      // exp(-lv); lv~N(0,1): safe
    params[((c * D + k) << 8) | i] =
        make_float4(-0.5f * LOG2E * ev,
                    LOG2E * mu * ev,
                    -0.5f * LOG2E * fmaf(mu * mu, ev, lv),
                    __builtin_amdgcn_exp2f(0.5f * LOG2E * lv));
}

// Build L and h*L' per node. 512 blocks = 128 ck x 4 segments; 1 node/thread.
// Per comp: 2 fma (arg) + exp + add + fma(2*ap-B) + fma(dacc) -> trans-bound.
__global__ __launch_bounds__(256) void ktable(const float4* __restrict__ params,
                                              float2* __restrict__ table)
{
    const int bid = blockIdx.x;
    const int ck  = bid >> 2;
    const int g   = ((bid & 3) << 8) | threadIdx.x;   // node 0..1023
    const float4* __restrict__ pk = params + (ck << 8);
    const float z = fmaf((float)g, HH, ZMIN);
    float acc = 0.f, dacc = 0.f;
#pragma unroll 8
    for (int i = 0; i < AGG; ++i) {
        const float4 p  = pk[i];
        const float ap  = fmaf(p.x, z, p.y);          // A z + B
        const float w   = __builtin_amdgcn_exp2f(fmaf(ap, z, p.z));
        acc += w;
        dacc = fmaf(w, fmaf(2.0f, ap, -p.y), dacc);   // arg' = 2Az+B = 2*ap - B
    }
    const float accg = fmaxf(acc, 1e-30f);            // unused far nodes: no NaN/inf issues
    table[(ck << 10) | g] =
        make_float2(__builtin_amdgcn_logf(accg),
                    dacc * __builtin_amdgcn_rcpf(accg) * HH);
}

// Exact 256-exp fallback for |z| > ZOOB (expected ~never; masked lanes only).
static __device__ __noinline__ float exact_log2q(const float4* __restrict__ pk, float z)
{
    float acc = 0.f;
    for (int i = 0; i < AGG; ++i) {
        const float4 p = pk[i];
        acc += __builtin_amdgcn_exp2f(fmaf(fmaf(p.x, z, p.y), z, p.z));
    }
    return __builtin_amdgcn_logf(fmaxf(acc, 1e-30f));
}

__global__ __launch_bounds__(256) void keval(const float* __restrict__ eps,
                                             const float4* __restrict__ params,
                                             const float2* __restrict__ table,
                                             float* __restrict__ partial,
                                             unsigned* __restrict__ counter,
                                             float* __restrict__ out)
{
    constexpr float LN2 = 0.6931471805599453f;
    const int bid = blockIdx.x;
    const int ck  = bid >> 2;                 // c*D + k
    const int q   = bid & 3;
    const int c   = ck >> 5;
    const int k   = ck & (D - 1);
    const int j0  = q * JB;
    const int t   = threadIdx.x;
    const float4* __restrict__ pk = params + (ck << 8);

    // Issue scattered eps gathers first (latency hides under table staging).
    float evv[TJ];
#pragma unroll
    for (int u = 0; u < TJ; ++u)
        evv[u] = eps[(size_t)(c * M + j0 + t + 256 * u) * D + k];

    // Stage this ck's table: 1024 float2 = 8KB, coalesced.
    __shared__ float2 tab[TN];
    const float2* __restrict__ gt = table + (ck << 10);
    tab[t]       = gt[t];
    tab[t + 256] = gt[t + 256];
    tab[t + 512] = gt[t + 512];
    tab[t + 768] = gt[t + 768];
    __syncthreads();

    float r = 0.f;
#pragma unroll
    for (int u = 0; u < TJ; ++u) {
        const int j    = j0 + t + 256 * u;
        const float4 p = pk[j >> 5];                   // own component (scalar path)
        const float mu = -0.5f * p.y * __builtin_amdgcn_rcpf(p.x);
        const float z  = fmaf(evv[u], p.w, mu);

        // cubic Hermite on the staged table
        const float zc = fminf(fmaxf(z, -ZCLAMP), ZCLAMP);
        const float x  = fmaf(zc, INVH, 512.0f);       // (zc - ZMIN)*INVH
        const float fg = floorf(x);
        const float f  = x - fg;
        const int  ig  = (int)fg;                      // in [1,1022]
        const float2 n0 = tab[ig];
        const float2 n1 = tab[ig + 1];
        const float dl  = n1.x - n0.x;
        const float c2  = 3.0f * dl - 2.0f * n0.y - n1.y;
        const float c3  = n0.y + n1.y - 2.0f * dl;
        float L = fmaf(f, fmaf(f, fmaf(f, c3, c2), n0.y), n0.x);
        if (fabsf(z) > ZOOB) L = exact_log2q(pk, z);   // ~never taken
        r += fmaf(LN2, L, 0.5f * z * z);
    }

    // deterministic block reduction
    for (int off = 32; off > 0; off >>= 1) r += __shfl_down(r, off, 64);
    __shared__ float wsum[4];
    if ((t & 63) == 0) wsum[t >> 6] = r;
    __syncthreads();

    // last-block final reduction (deterministic fixed-order sum)
    __shared__ int isLast;
    if (t == 0) {
        partial[bid] = (wsum[0] + wsum[1]) + (wsum[2] + wsum[3]);
        __threadfence();
        const unsigned old = atomicAdd(counter, 1u);
        isLast = (old == (unsigned)(NBLK - 1));
    }
    __syncthreads();
    if (isLast) {
        __threadfence();
        double s = 0.0;
#pragma unroll
        for (int i = 0; i < NBLK / 256; ++i) s += (double)partial[i * 256 + t];
        __shared__ double sd[256];
        sd[t] = s;
        __syncthreads();
        for (int off = 128; off > 0; off >>= 1) {
            if (t < off) sd[t] += sd[t + off];
            __syncthreads();
        }
        if (t == 0)
            out[0] = (float)(sd[0] * (1.0 / (double)(NC * M))
                             - (double)D * 5.545177444479562);   // - D*ln(256)
    }
}

// Fallback (ws too small for the table): proven r8 path, ~48us.
__global__ __launch_bounds__(256) void kmain(const float* __restrict__ eps,
                                             const float4* __restrict__ params,
                                             float* __restrict__ partial,
                                             unsigned* __restrict__ counter,
                                             float* __restrict__ out)
{
    constexpr float LN2 = 0.6931471805599453f;
    const int bid = blockIdx.x;
    const int ck  = bid >> 2;
    const int q   = bid & 3;
    const int c   = ck >> 5;
    const int k   = ck & (D - 1);
    const int j0  = q * JB;
    const int t   = threadIdx.x;
    const float4* __restrict__ pk = params + (ck << 8);

    float evv[TJ];
#pragma unroll
    for (int u = 0; u < TJ; ++u)
        evv[u] = eps[(size_t)(c * M + j0 + t + 256 * u) * D + k];

    float zv[TJ], acc[TJ];
#pragma unroll
    for (int u = 0; u < TJ; ++u) {
        const float4 p = pk[(t + 256 * u) >> 5];
        const float mu = -0.5f * p.y * __builtin_amdgcn_rcpf(p.x);
        zv[u]  = fmaf(evv[u], p.w, mu);
        acc[u] = 0.f;
    }
#pragma unroll 4
    for (int i = 0; i < AGG; ++i) {
        const float4 p = pk[i];
#pragma unroll
        for (int u = 0; u < TJ; ++u)
            acc[u] += __builtin_amdgcn_exp2f(fmaf(fmaf(p.x, zv[u], p.y), zv[u], p.z));
    }
    float r = 0.f;
#pragma unroll
    for (int u = 0; u < TJ; ++u)
        r += LN2 * __builtin_amdgcn_logf(acc[u]) + 0.5f * zv[u] * zv[u];

    for (int off = 32; off > 0; off >>= 1) r += __shfl_down(r, off, 64);
    __shared__ float wsum[4];
    if ((t & 63) == 0) wsum[t >> 6] = r;
    __syncthreads();
    __shared__ int isLast;
    if (t == 0) {
        partial[bid] = (wsum[0] + wsum[1]) + (wsum[2] + wsum[3]);
        __threadfence();
        const unsigned old = atomicAdd(counter, 1u);
        isLast = (old == (unsigned)(NBLK - 1));
    }
    __syncthreads();
    if (isLast) {
        __threadfence();
        double s = 0.0;
#pragma unroll
        for (int i = 0; i < NBLK / 256; ++i) s += (double)partial[i * 256 + t];
        __shared__ double sd[256];
        sd[t] = s;
        __syncthreads();
        for (int off = 128; off > 0; off >>= 1) {
            if (t < off) sd[t] += sd[t + off];
            __syncthreads();
        }
        if (t == 0)
            out[0] = (float)(sd[0] * (1.0 / (double)(NC * M))
                             - (double)D * 5.545177444479562);
    }
}

extern "C" void kernel_launch(void* const* d_in, const int* in_sizes, int n_in,
                              void* d_out, int out_size, void* d_ws, size_t ws_size,
                              hipStream_t stream)
{
    const float* mean   = (const float*)d_in[0];
    const float* logvar = (const float*)d_in[1];
    const float* eps    = (const float*)d_in[2];
    float* out = (float*)d_out;

    unsigned* counter = (unsigned*)d_ws;
    float*    partial = (float*)((char*)d_ws + WS_PARTIAL);
    float4*   params  = (float4*)((char*)d_ws + WS_PARAMS);
    float2*   table   = (float2*)((char*)d_ws + WS_TABLE);

    ksetup<<<(B * D) / 256, 256, 0, stream>>>(mean, logvar, params, counter);
    if (ws_size >= (size_t)WS_NEED) {
        ktable<<<NC * D * 4, 256, 0, stream>>>(params, table);
        keval<<<NBLK, 256, 0, stream>>>(eps, params, table, partial, counter, out);
    } else {
        kmain<<<NBLK, 256, 0, stream>>>(eps, params, partial, counter, out);
    }
}